// Round 6
// baseline (244.067 us; speedup 1.0000x reference)
//
#include <hip/hip_runtime.h>
#include <math.h>

#define B_ 64
#define L_ 512
#define N_ 321
#define P_ 720
#define E_ 8
#define R_ 32
#define CID_ 32
#define H_ 64
#define ER_ 256
#define KB2 288   // ER_ + 8 bias-rank + 1 mean + 23 zero-pad (9 K-steps of 32)

typedef __attribute__((ext_vector_type(8))) short bf16x8;
typedef __attribute__((ext_vector_type(4))) float f32x4;
typedef __attribute__((ext_vector_type(8))) unsigned short u16x8;
typedef __attribute__((ext_vector_type(4))) unsigned short u16x4;

// workspace layout (float offsets)
#define OFF_GATE 0                       // N*E = 2568
#define OFF_CS1  (N_*E_)                 // 256 floats
#define OFF_W1K  (OFF_CS1 + ER_)         // bf16 256*512
#define OFF_W2X  (OFF_W1K + ER_*L_/2)    // bf16 720*288

__device__ __forceinline__ unsigned short f2bf(float f) {
    unsigned u = __float_as_uint(f);
    u += 0x7fffu + ((u >> 16) & 1u);
    return (unsigned short)(u >> 16);
}
__device__ __forceinline__ float bf2f(unsigned short h) {
    return __uint_as_float(((unsigned)h) << 16);
}

// ---------------- router ----------------------------------------------------
__global__ void router_kernel(const float* __restrict__ ident,
                              const float* __restrict__ rw1, const float* __restrict__ rb1,
                              const float* __restrict__ rw2, const float* __restrict__ rb2,
                              float* __restrict__ gate) {
    int n = blockIdx.x;
    int t = threadIdx.x;  // 0..63
    __shared__ float hid[H_];
    __shared__ float lg[E_];
    float acc = rb1[t];
    #pragma unroll
    for (int c = 0; c < CID_; ++c)
        acc = fmaf(ident[n*CID_ + c], rw1[c*H_ + t], acc);
    hid[t] = fmaxf(acc, 0.f);
    __syncthreads();
    if (t < E_) {
        float a = rb2[t];
        #pragma unroll
        for (int h = 0; h < H_; ++h) a = fmaf(hid[h], rw2[h*E_ + t], a);
        lg[t] = a;
    }
    __syncthreads();
    if (t == 0) {
        float m = lg[0];
        #pragma unroll
        for (int e = 1; e < E_; ++e) m = fmaxf(m, lg[e]);
        float s = 0.f, ex[E_];
        #pragma unroll
        for (int e = 0; e < E_; ++e) { ex[e] = expf(lg[e] - m); s += ex[e]; }
        float inv = 1.f / s;
        #pragma unroll
        for (int e = 0; e < E_; ++e) gate[n*E_ + e] = ex[e] * inv;
    }
}

// ---------------- prep: w1k [er][l], w2x [p][288], cs1 ----------------------
__global__ void prep_kernel(const float* __restrict__ w1, const float* __restrict__ w2,
                            const float* __restrict__ bias,
                            unsigned short* __restrict__ w1k, unsigned short* __restrict__ w2x,
                            float* __restrict__ cs1) {
    __shared__ float red[16][32];
    int bid = blockIdx.x, t = threadIdx.x;
    if (bid < 256) {                  // w1k [er][l]: 256*512 elems
        int g = bid*512 + t;
        int er = g >> 9, l = g & 511;
        w1k[g] = f2bf(w1[(size_t)(er >> 5)*(L_*R_) + (size_t)l*R_ + (er & 31)]);
    } else if (bid < 256 + 720) {     // w2x row p: K-extended
        int p = bid - 256;
        if (t < KB2) {
            unsigned short v;
            if (t < ER_)            v = f2bf(w2[(size_t)t*P_ + p]);
            else if (t < ER_ + E_)  v = f2bf(bias[(size_t)(t - ER_)*P_ + p]);
            else if (t == ER_ + E_) v = 0x3f80;  // bf16(1.0) for the mean lane
            else                    v = 0;
            w2x[(size_t)p*KB2 + t] = v;
        }
    } else {                          // cs1: 8 blocks, one expert each
        int e = bid - 976;
        int q = t >> 5, r = t & 31;
        float s = 0.f;
        for (int l = q; l < L_; l += 16)
            s += bf2f(f2bf(w1[(size_t)e*(L_*R_) + (size_t)l*R_ + r]));
        red[q][r] = s;
        __syncthreads();
        if (q == 0) {
            #pragma unroll
            for (int qq = 1; qq < 16; ++qq) s += red[qq][r];
            cs1[e*32 + r] = s;
        }
    }
}

// ---------------- fused kernel ----------------------------------------------
// Per (b, 64-n-tile), XCD-grouped so all 6 tiles of one b share an L2:
//  Stage A (identical structure to R5): hgt[n][0:288] built in LDS.
//  Stage B: swapped-operand MFMA (D rows = n) -> direct f32x4 stores, no patch.
#define HG_STRIDE 296   // u16
#define SM_AS   0               // u16 [2][256][40] = 40960 B (union hgt [64][296] = 37888)
#define SM_BS   40960           // u16 [2][64][40]  = 10240 B (union red/msd, dead after loop)
#define SM_TOT  51200

__global__ __launch_bounds__(512, 6) void fused_kernel(
        const float* __restrict__ x, const unsigned short* __restrict__ w1k,
        const unsigned short* __restrict__ w2x, const float* __restrict__ gate,
        const float* __restrict__ cs1, float* __restrict__ out) {
    __shared__ __align__(16) char smem[SM_TOT];
    unsigned short* As  = (unsigned short*)(smem + SM_AS);   // [2][256][40]
    unsigned short* Bs  = (unsigned short*)(smem + SM_BS);   // [2][64][40]
    float* red1  = (float*)(smem + SM_BS);                   // [8][64] (union Bs[0])
    float* red2  = red1 + 512;
    float* meanS = (float*)(smem + SM_BS + 4096);            // [64]
    float* sdS   = meanS + 64;
    unsigned short* hgt = (unsigned short*)(smem + SM_AS);   // [64][296] (union As)

    // XCD-bijective remap: xcd = bid&7 gets b = xcd*8..xcd*8+7, tiles adjacent
    const int bid = blockIdx.x;
    const int xcd = bid & 7;
    const int idx = bid >> 3;            // 0..47
    const int b   = (xcd << 3) + idx / 6;
    const int n0  = (idx % 6) * 64;

    const int tid = threadIdx.x;
    const int lane = tid & 63;
    const int wave = tid >> 6;          // 0..7
    const int wm = wave >> 1;           // er-base = wm*64
    const int wn = wave & 1;            // n-base = wn*32
    const int l15 = lane & 15;
    const int kgrp = lane >> 4;         // 0..3

    // ---- stage A ----
    const int arow = tid >> 1;          // 0..255
    const int acol = (tid & 1) * 16;    // 0/16
    const int xn  = tid & 63;
    const int xkb = wave * 4;           // 0..28
    const float* xb = x + (size_t)b * L_ * N_;
    const int gn = n0 + xn;
    const bool nvalid = (gn < N_);

    float s1 = 0.f, s2 = 0.f;
    float xr[3][4];
    u16x8 ar[2][2];

    f32x4 acc[4][2];
    #pragma unroll
    for (int i = 0; i < 4; ++i)
        #pragma unroll
        for (int j = 0; j < 2; ++j) acc[i][j] = (f32x4){0.f,0.f,0.f,0.f};

#define LOADX(s_, t_) { const int k0 = (t_)*32;                                  \
    _Pragma("unroll")                                                            \
    for (int i_ = 0; i_ < 4; ++i_)                                               \
        xr[s_][i_] = nvalid ? xb[(size_t)(k0 + xkb + i_)*N_ + gn] : 0.f; }
#define LOADA(s_, t_) { const int k0 = (t_)*32;                                  \
    ar[s_][0] = *(const u16x8*)&w1k[(size_t)arow*L_ + k0 + acol];                \
    ar[s_][1] = *(const u16x8*)&w1k[(size_t)arow*L_ + k0 + acol + 8]; }
#define STAGE(nb_, xs_, as_) {                                                   \
    *(u16x8*)&As[(size_t)((nb_)*256 + arow)*40 + acol]     = ar[as_][0];         \
    *(u16x8*)&As[(size_t)((nb_)*256 + arow)*40 + acol + 8] = ar[as_][1];         \
    u16x4 bp_;                                                                   \
    _Pragma("unroll")                                                            \
    for (int i_ = 0; i_ < 4; ++i_) {                                             \
        float v_ = xr[xs_][i_]; s1 += v_; s2 = fmaf(v_, v_, s2);                 \
        bp_[i_] = f2bf(v_); }                                                    \
    *(u16x4*)&Bs[(size_t)((nb_)*64 + xn)*40 + xkb] = bp_; }

    LOADX(0, 0); LOADA(0, 0);
    LOADX(1, 1); LOADA(1, 1);
    LOADX(2, 2);
    STAGE(0, 0, 0);
    __syncthreads();

    #pragma unroll
    for (int t = 0; t < 16; ++t) {
        if (t + 3 < 16) LOADX((t + 3) % 3, t + 3);
        if (t + 2 < 16) LOADA((t + 2) & 1, t + 2);
        const int cur = t & 1;
        bf16x8 af[4], bfv[2];
        #pragma unroll
        for (int fm = 0; fm < 4; ++fm)
            af[fm] = *(const bf16x8*)&As[(size_t)(cur*256 + wm*64 + fm*16 + l15)*40 + kgrp*8];
        #pragma unroll
        for (int fn = 0; fn < 2; ++fn)
            bfv[fn] = *(const bf16x8*)&Bs[(size_t)(cur*64 + wn*32 + fn*16 + l15)*40 + kgrp*8];
        #pragma unroll
        for (int fm = 0; fm < 4; ++fm)
            #pragma unroll
            for (int fn = 0; fn < 2; ++fn)
                acc[fm][fn] = __builtin_amdgcn_mfma_f32_16x16x32_bf16(af[fm], bfv[fn], acc[fm][fn], 0, 0, 0);
        if (t < 15) STAGE((t + 1) & 1, (t + 1) % 3, (t + 1) & 1);
        __syncthreads();
    }

    // ---- stats (red unions Bs[0], dead now) ----
    red1[wave*64 + xn] = s1;
    red2[wave*64 + xn] = s2;
    __syncthreads();
    if (tid < 64) {
        float a = 0.f, q = 0.f;
        #pragma unroll
        for (int kk = 0; kk < 8; ++kk) { a += red1[kk*64 + tid]; q += red2[kk*64 + tid]; }
        float mean = a * (1.f/L_);
        float var = (q - (float)L_*mean*mean) * (1.f/(L_-1));
        var = fmaxf(var, 0.f);
        meanS[tid] = mean;
        sdS[tid]   = sqrtf(var) + 1e-6f;
    }
    __syncthreads();

    // ---- stage A epilogue: write hgt (unions As; all As reads done) ----
    #pragma unroll
    for (int fm = 0; fm < 4; ++fm) {
        int er0 = wm*64 + fm*16 + kgrp*4;
        int e = er0 >> 5;
        f32x4 c4 = *(const f32x4*)&cs1[er0];
        #pragma unroll
        for (int fn = 0; fn < 2; ++fn) {
            int nl = wn*32 + fn*16 + l15;
            int gnn = n0 + nl; if (gnn > N_-1) gnn = N_-1;
            float g = gate[gnn*E_ + e];
            float m = meanS[nl];
            u16x4 pk;
            #pragma unroll
            for (int j = 0; j < 4; ++j)
                pk[j] = f2bf(g * (acc[fm][fn][j] - m * c4[j]));
            *(u16x4*)&hgt[(size_t)nl*HG_STRIDE + er0] = pk;
        }
    }
    {   // K-extension cols 256..287 for all 64 rows
        int nl = tid >> 3, seg = tid & 7;
        int gnn = n0 + nl; if (gnn > N_-1) gnn = N_-1;
        float sd = sdS[nl], m = meanS[nl];
        u16x4 pk;
        #pragma unroll
        for (int jj = 0; jj < 4; ++jj) {
            int k = seg*4 + jj;
            float v = (k < E_) ? gate[gnn*E_ + k] * sd : ((k == E_) ? m : 0.f);
            pk[jj] = f2bf(v);
        }
        *(u16x4*)&hgt[(size_t)nl*HG_STRIDE + ER_ + seg*4] = pk;
    }
    __syncthreads();

    // ---- stage B: swapped operands -> D rows = n (consecutive per lane) ----
    // o[fp][fn]: lane (l15,kgrp) holds out[n = n0+fn*16+kgrp*4+j][p = p0w+fp*16+l15]
    for (int pt = wave; pt < 23; pt += 8) {
        const int p0w = pt * 32;
        int pr0 = p0w + l15;       if (pr0 > P_-1) pr0 = P_-1;
        int pr1 = p0w + 16 + l15;  if (pr1 > P_-1) pr1 = P_-1;
        const unsigned short* bp0 = w2x + (size_t)pr0*KB2;
        const unsigned short* bp1 = w2x + (size_t)pr1*KB2;

        f32x4 o[2][4];
        #pragma unroll
        for (int i = 0; i < 2; ++i)
            #pragma unroll
            for (int j = 0; j < 4; ++j) o[i][j] = (f32x4){0.f,0.f,0.f,0.f};

        #pragma unroll
        for (int ks = 0; ks < 9; ++ks) {
            bf16x8 b0f = *(const bf16x8*)&bp0[ks*32 + kgrp*8];
            bf16x8 b1f = *(const bf16x8*)&bp1[ks*32 + kgrp*8];
            bf16x8 afr[4];
            #pragma unroll
            for (int fn = 0; fn < 4; ++fn)
                afr[fn] = *(const bf16x8*)&hgt[(size_t)(fn*16 + l15)*HG_STRIDE + ks*32 + kgrp*8];
            #pragma unroll
            for (int fn = 0; fn < 4; ++fn) {
                o[0][fn] = __builtin_amdgcn_mfma_f32_16x16x32_bf16(afr[fn], b0f, o[0][fn], 0, 0, 0);
                o[1][fn] = __builtin_amdgcn_mfma_f32_16x16x32_bf16(afr[fn], b1f, o[1][fn], 0, 0, 0);
            }
        }

        #pragma unroll
        for (int fp = 0; fp < 2; ++fp) {
            int p = p0w + fp*16 + l15;
            if (p < P_) {
                float* orow = out + ((size_t)b*P_ + p)*N_;
                #pragma unroll
                for (int fn = 0; fn < 4; ++fn) {
                    int n = n0 + fn*16 + kgrp*4;
                    if (n + 3 < N_) {
                        *(f32x4*)&orow[n] = o[fp][fn];
                    } else {
                        #pragma unroll
                        for (int j = 0; j < 4; ++j)
                            if (n + j < N_) orow[n + j] = o[fp][fn][j];
                    }
                }
            }
        }
    }
#undef LOADX
#undef LOADA
#undef STAGE
}

extern "C" void kernel_launch(void* const* d_in, const int* in_sizes, int n_in,
                              void* d_out, int out_size, void* d_ws, size_t ws_size,
                              hipStream_t stream) {
    const float* x     = (const float*)d_in[0];
    const float* ident = (const float*)d_in[1];
    const float* rw1   = (const float*)d_in[2];
    const float* rb1   = (const float*)d_in[3];
    const float* rw2   = (const float*)d_in[4];
    const float* rb2   = (const float*)d_in[5];
    const float* w1    = (const float*)d_in[6];
    const float* w2    = (const float*)d_in[7];
    const float* bias  = (const float*)d_in[8];
    float* out = (float*)d_out;
    float* ws  = (float*)d_ws;

    float* gate = ws + OFF_GATE;
    float* cs1  = ws + OFF_CS1;
    unsigned short* w1k = (unsigned short*)(ws + OFF_W1K);
    unsigned short* w2x = (unsigned short*)(ws + OFF_W2X);

    router_kernel<<<N_, 64, 0, stream>>>(ident, rw1, rb1, rw2, rb2, gate);
    prep_kernel<<<256 + 720 + 8, 512, 0, stream>>>(w1, w2, bias, w1k, w2x, cs1);
    fused_kernel<<<dim3(6*B_), 512, 0, stream>>>(x, w1k, w2x, gate, cs1, out);
}

// Round 7
// 112.428 us; speedup vs baseline: 2.1709x; 2.1709x over previous
//
#include <hip/hip_runtime.h>
#include <math.h>

#define B_ 64
#define L_ 512
#define N_ 321
#define P_ 720
#define E_ 8
#define R_ 32
#define CID_ 32
#define H_ 64
#define ER_ 256
#define KB2 288   // ER_ + 8 bias-rank + 1 mean + 23 zero-pad (9 K-steps of 32)

typedef __attribute__((ext_vector_type(8))) short bf16x8;
typedef __attribute__((ext_vector_type(4))) float f32x4;
typedef __attribute__((ext_vector_type(8))) unsigned short u16x8;
typedef __attribute__((ext_vector_type(4))) unsigned short u16x4;
typedef __attribute__((ext_vector_type(2))) unsigned short u16x2;

// workspace layout (float offsets)
#define OFF_GATE 0                       // N*E = 2568
#define OFF_CS1  (N_*E_)                 // 256 floats
#define OFF_W1K  (OFF_CS1 + ER_)         // bf16 256*512
#define OFF_W2X  (OFF_W1K + ER_*L_/2)    // bf16 720*288

__device__ __forceinline__ unsigned short f2bf(float f) {
    unsigned u = __float_as_uint(f);
    u += 0x7fffu + ((u >> 16) & 1u);
    return (unsigned short)(u >> 16);
}
__device__ __forceinline__ float bf2f(unsigned short h) {
    return __uint_as_float(((unsigned)h) << 16);
}

// ---------------- router ----------------------------------------------------
__global__ void router_kernel(const float* __restrict__ ident,
                              const float* __restrict__ rw1, const float* __restrict__ rb1,
                              const float* __restrict__ rw2, const float* __restrict__ rb2,
                              float* __restrict__ gate) {
    int n = blockIdx.x;
    int t = threadIdx.x;  // 0..63
    __shared__ float hid[H_];
    __shared__ float lg[E_];
    float acc = rb1[t];
    #pragma unroll
    for (int c = 0; c < CID_; ++c)
        acc = fmaf(ident[n*CID_ + c], rw1[c*H_ + t], acc);
    hid[t] = fmaxf(acc, 0.f);
    __syncthreads();
    if (t < E_) {
        float a = rb2[t];
        #pragma unroll
        for (int h = 0; h < H_; ++h) a = fmaf(hid[h], rw2[h*E_ + t], a);
        lg[t] = a;
    }
    __syncthreads();
    if (t == 0) {
        float m = lg[0];
        #pragma unroll
        for (int e = 1; e < E_; ++e) m = fmaxf(m, lg[e]);
        float s = 0.f, ex[E_];
        #pragma unroll
        for (int e = 0; e < E_; ++e) { ex[e] = expf(lg[e] - m); s += ex[e]; }
        float inv = 1.f / s;
        #pragma unroll
        for (int e = 0; e < E_; ++e) gate[n*E_ + e] = ex[e] * inv;
    }
}

// ---------------- prep: w1k [er][l], w2x [p][288], cs1 ----------------------
__global__ void prep_kernel(const float* __restrict__ w1, const float* __restrict__ w2,
                            const float* __restrict__ bias,
                            unsigned short* __restrict__ w1k, unsigned short* __restrict__ w2x,
                            float* __restrict__ cs1) {
    __shared__ float red[16][32];
    int bid = blockIdx.x, t = threadIdx.x;
    if (bid < 256) {                  // w1k [er][l]: 256*512 elems
        int g = bid*512 + t;
        int er = g >> 9, l = g & 511;
        w1k[g] = f2bf(w1[(size_t)(er >> 5)*(L_*R_) + (size_t)l*R_ + (er & 31)]);
    } else if (bid < 256 + 720) {     // w2x row p: K-extended
        int p = bid - 256;
        if (t < KB2) {
            unsigned short v;
            if (t < ER_)            v = f2bf(w2[(size_t)t*P_ + p]);
            else if (t < ER_ + E_)  v = f2bf(bias[(size_t)(t - ER_)*P_ + p]);
            else if (t == ER_ + E_) v = 0x3f80;  // bf16(1.0) for the mean lane
            else                    v = 0;
            w2x[(size_t)p*KB2 + t] = v;
        }
    } else {                          // cs1: 8 blocks, one expert each
        int e = bid - 976;
        int q = t >> 5, r = t & 31;
        float s = 0.f;
        for (int l = q; l < L_; l += 16)
            s += bf2f(f2bf(w1[(size_t)e*(L_*R_) + (size_t)l*R_ + r]));
        red[q][r] = s;
        __syncthreads();
        if (q == 0) {
            #pragma unroll
            for (int qq = 1; qq < 16; ++qq) s += red[qq][r];
            cs1[e*32 + r] = s;
        }
    }
}

// ---------------- fused kernel, BN=32 ---------------------------------------
// grid = 704 blocks: xcd = bid&7, all 11 n-tiles of each b on one XCD.
// Stage A: 8 waves x (32er x 32n), w1k A-frags direct from L2 (no As LDS),
//          x staged via LDS ring; fused mean/std.
// Stage B: per-wave 32p x 32n tiles, K=288 (bias/mean folded), patch-transpose
//          epilogue -> 128B-run coalesced stores. No manual waitcnt.
#define HG_STRIDE 296   // u16
#define SM_HGT   0                       // u16 [32][296] = 18944 (unions Bs, red)
#define SM_BS    0                       //   u16 [2][32][40] = 5120
#define SM_RED   5120                    //   f32 [16][32] x2 = 4096
#define SM_MSD   18944                   // f32 [32]x2 = 256
#define SM_PATCH 19200                   // f32 [8][16][36] = 18432
#define SM_TOT   37632

__global__ __launch_bounds__(512, 6) void fused_kernel(
        const float* __restrict__ x, const unsigned short* __restrict__ w1k,
        const unsigned short* __restrict__ w2x, const float* __restrict__ gate,
        const float* __restrict__ cs1, float* __restrict__ out) {
    __shared__ __align__(16) char smem[SM_TOT];
    unsigned short* hgt = (unsigned short*)(smem + SM_HGT);  // [32][296]
    unsigned short* Bs  = (unsigned short*)(smem + SM_BS);   // [2][32][40]
    float* red1  = (float*)(smem + SM_RED);                  // [16][32]
    float* red2  = red1 + 512;
    float* meanS = (float*)(smem + SM_MSD);                  // [32]
    float* sdS   = meanS + 32;

    // XCD-grouped bijective remap
    const int bid = blockIdx.x;
    const int xcd = bid & 7;
    const int idx = bid >> 3;            // 0..87
    const int b   = (xcd << 3) + idx / 11;
    const int n0  = (idx % 11) * 32;

    const int tid  = threadIdx.x;
    const int lane = tid & 63;
    const int wave = tid >> 6;          // 0..7 == expert id in stage A
    const int l15  = lane & 15;
    const int kgrp = lane >> 4;         // 0..3

    // ---- stage A ----
    const int xn  = tid & 31;           // n within tile
    const int xks = tid >> 5;           // 0..15, k-slice (2 k each)
    const float* xb = x + (size_t)b * L_ * N_;
    const int gn = n0 + xn;
    const bool nvalid = (gn < N_);

    float s1 = 0.f, s2 = 0.f;
    float xr[3][2];
    bf16x8 af[2][2];

    f32x4 acc[2][2];
    #pragma unroll
    for (int i = 0; i < 2; ++i)
        #pragma unroll
        for (int j = 0; j < 2; ++j) acc[i][j] = (f32x4){0.f,0.f,0.f,0.f};

#define LOADX(s_, t_) { const int k0 = (t_)*32 + xks*2;                          \
    xr[s_][0] = nvalid ? xb[(size_t)k0*N_ + gn] : 0.f;                           \
    xr[s_][1] = nvalid ? xb[(size_t)(k0+1)*N_ + gn] : 0.f; }
#define LOADAF(s_, t_) {                                                         \
    af[s_][0] = *(const bf16x8*)&w1k[(size_t)(wave*32 + l15)*L_ + (t_)*32 + kgrp*8];      \
    af[s_][1] = *(const bf16x8*)&w1k[(size_t)(wave*32 + 16 + l15)*L_ + (t_)*32 + kgrp*8]; }
#define STAGE(nb_, xs_) {                                                        \
    float v0_ = xr[xs_][0], v1_ = xr[xs_][1];                                    \
    s1 += v0_ + v1_; s2 = fmaf(v0_, v0_, s2); s2 = fmaf(v1_, v1_, s2);           \
    u16x2 bp_; bp_[0] = f2bf(v0_); bp_[1] = f2bf(v1_);                           \
    *(u16x2*)&Bs[(size_t)((nb_)*32 + xn)*40 + xks*2] = bp_; }

    LOADAF(0, 0); LOADAF(1, 1);
    LOADX(0, 0); LOADX(1, 1); LOADX(2, 2);
    STAGE(0, 0);
    __syncthreads();

    #pragma unroll
    for (int t = 0; t < 16; ++t) {
        const int cur = t & 1;
        if (t + 3 < 16) LOADX((t + 3) % 3, t + 3);
        bf16x8 bfv[2];
        #pragma unroll
        for (int fn = 0; fn < 2; ++fn)
            bfv[fn] = *(const bf16x8*)&Bs[(size_t)(cur*32 + fn*16 + l15)*40 + kgrp*8];
        #pragma unroll
        for (int fm = 0; fm < 2; ++fm)
            #pragma unroll
            for (int fn = 0; fn < 2; ++fn)
                acc[fm][fn] = __builtin_amdgcn_mfma_f32_16x16x32_bf16(af[cur][fm], bfv[fn], acc[fm][fn], 0, 0, 0);
        if (t + 2 < 16) LOADAF(cur, t + 2);     // slot `cur` consumed above
        if (t < 15) STAGE((t + 1) & 1, (t + 1) % 3);
        __syncthreads();
    }

    // ---- stats (red unions Bs region, Bs dead after loop) ----
    red1[xks*32 + xn] = s1;
    red2[xks*32 + xn] = s2;
    __syncthreads();
    if (tid < 32) {
        float a = 0.f, q = 0.f;
        #pragma unroll
        for (int kk = 0; kk < 16; ++kk) { a += red1[kk*32 + tid]; q += red2[kk*32 + tid]; }
        float mean = a * (1.f/L_);
        float var = (q - (float)L_*mean*mean) * (1.f/(L_-1));
        var = fmaxf(var, 0.f);
        meanS[tid] = mean;
        sdS[tid]   = sqrtf(var) + 1e-6f;
    }
    __syncthreads();

    // ---- stage A epilogue: write hgt (overwrites Bs/red region) ----
    #pragma unroll
    for (int fm = 0; fm < 2; ++fm) {
        int er0 = wave*32 + fm*16 + kgrp*4;   // expert = wave
        f32x4 c4 = *(const f32x4*)&cs1[er0];
        #pragma unroll
        for (int fn = 0; fn < 2; ++fn) {
            int nl = fn*16 + l15;
            int gnn = n0 + nl; if (gnn > N_-1) gnn = N_-1;
            float g = gate[gnn*E_ + wave];
            float m = meanS[nl];
            u16x4 pk;
            #pragma unroll
            for (int j = 0; j < 4; ++j)
                pk[j] = f2bf(g * (acc[fm][fn][j] - m * c4[j]));
            *(u16x4*)&hgt[(size_t)nl*HG_STRIDE + er0] = pk;
        }
    }
    if (tid < 256) {   // K-extension cols 256..287 for 32 rows
        int nl = tid >> 3, seg = tid & 7;
        int gnn = n0 + nl; if (gnn > N_-1) gnn = N_-1;
        float sd = sdS[nl], m = meanS[nl];
        u16x4 pk;
        #pragma unroll
        for (int jj = 0; jj < 4; ++jj) {
            int k = seg*4 + jj;
            float v = (k < E_) ? gate[gnn*E_ + k] * sd : ((k == E_) ? m : 0.f);
            pk[jj] = f2bf(v);
        }
        *(u16x4*)&hgt[(size_t)nl*HG_STRIDE + ER_ + seg*4] = pk;
    }
    __syncthreads();

    // ---- stage B: per-wave 32p x 32n, K=288, patch-transpose stores ----
    float* patch = (float*)(smem + SM_PATCH) + wave * 576;   // [16][36]
    for (int pt = wave; pt < 23; pt += 8) {
        const int p0w = pt * 32;
        int pr0 = p0w + l15;       if (pr0 > P_-1) pr0 = P_-1;
        int pr1 = p0w + 16 + l15;  if (pr1 > P_-1) pr1 = P_-1;
        const unsigned short* ap0 = w2x + (size_t)pr0*KB2;
        const unsigned short* ap1 = w2x + (size_t)pr1*KB2;

        f32x4 o[2][2];
        #pragma unroll
        for (int i = 0; i < 2; ++i)
            #pragma unroll
            for (int j = 0; j < 2; ++j) o[i][j] = (f32x4){0.f,0.f,0.f,0.f};

        #pragma unroll
        for (int ks = 0; ks < 9; ++ks) {
            bf16x8 a0 = *(const bf16x8*)&ap0[ks*32 + kgrp*8];
            bf16x8 a1 = *(const bf16x8*)&ap1[ks*32 + kgrp*8];
            bf16x8 b0 = *(const bf16x8*)&hgt[(size_t)l15*HG_STRIDE + ks*32 + kgrp*8];
            bf16x8 b1 = *(const bf16x8*)&hgt[(size_t)(16 + l15)*HG_STRIDE + ks*32 + kgrp*8];
            o[0][0] = __builtin_amdgcn_mfma_f32_16x16x32_bf16(a0, b0, o[0][0], 0, 0, 0);
            o[0][1] = __builtin_amdgcn_mfma_f32_16x16x32_bf16(a0, b1, o[0][1], 0, 0, 0);
            o[1][0] = __builtin_amdgcn_mfma_f32_16x16x32_bf16(a1, b0, o[1][0], 0, 0, 0);
            o[1][1] = __builtin_amdgcn_mfma_f32_16x16x32_bf16(a1, b1, o[1][1], 0, 0, 0);
        }

        // patch-transpose: D(row p = kgrp*4+j, col n = fn*16+l15) -> n-major rows
        #pragma unroll
        for (int fp = 0; fp < 2; ++fp) {
            #pragma unroll
            for (int fn = 0; fn < 2; ++fn)
                #pragma unroll
                for (int j = 0; j < 4; ++j)
                    patch[(kgrp*4 + j)*36 + fn*16 + l15] = o[fp][fn][j];
            // compiler inserts lgkmcnt for the write->read dependence
            #pragma unroll
            for (int h = 0; h < 2; ++h) {
                int prow = p0w + fp*16 + h*8 + (lane >> 3);
                f32x4 v = *(const f32x4*)&patch[(h*8 + (lane >> 3))*36 + (lane & 7)*4];
                int n = n0 + (lane & 7)*4;
                if (prow < P_) {
                    float* orow = out + ((size_t)b*P_ + prow)*N_;
                    if (n + 3 < N_) {
                        *(f32x4*)&orow[n] = v;
                    } else {
                        #pragma unroll
                        for (int j = 0; j < 4; ++j)
                            if (n + j < N_) orow[n + j] = v[j];
                    }
                }
            }
        }
    }
#undef LOADX
#undef LOADAF
#undef STAGE
}

extern "C" void kernel_launch(void* const* d_in, const int* in_sizes, int n_in,
                              void* d_out, int out_size, void* d_ws, size_t ws_size,
                              hipStream_t stream) {
    const float* x     = (const float*)d_in[0];
    const float* ident = (const float*)d_in[1];
    const float* rw1   = (const float*)d_in[2];
    const float* rb1   = (const float*)d_in[3];
    const float* rw2   = (const float*)d_in[4];
    const float* rb2   = (const float*)d_in[5];
    const float* w1    = (const float*)d_in[6];
    const float* w2    = (const float*)d_in[7];
    const float* bias  = (const float*)d_in[8];
    float* out = (float*)d_out;
    float* ws  = (float*)d_ws;

    float* gate = ws + OFF_GATE;
    float* cs1  = ws + OFF_CS1;
    unsigned short* w1k = (unsigned short*)(ws + OFF_W1K);
    unsigned short* w2x = (unsigned short*)(ws + OFF_W2X);

    router_kernel<<<N_, 64, 0, stream>>>(ident, rw1, rb1, rw2, rb2, gate);
    prep_kernel<<<256 + 720 + 8, 512, 0, stream>>>(w1, w2, bias, w1k, w2x, cs1);
    fused_kernel<<<dim3(11*B_), 512, 0, stream>>>(x, w1k, w2x, gate, cs1, out);
}

// Round 8
// 88.338 us; speedup vs baseline: 2.7629x; 1.2727x over previous
//
#include <hip/hip_runtime.h>
#include <math.h>

#define B_ 64
#define L_ 512
#define N_ 321
#define P_ 720
#define E_ 8
#define R_ 32
#define CID_ 32
#define H_ 64
#define ER_ 256
#define KB2 288      // ER_ + 8 bias-rank + 1 mean + 23 zero-pad
#define HGROWS 384   // 6 n-tiles x 64 (rows >= N_ written with junk, never used)

typedef __attribute__((ext_vector_type(8))) short bf16x8;
typedef __attribute__((ext_vector_type(4))) float f32x4;
typedef __attribute__((ext_vector_type(8))) unsigned short u16x8;
typedef __attribute__((ext_vector_type(4))) unsigned short u16x4;

// workspace layout (float offsets)
#define OFF_GATE 0                       // N*E = 2568
#define OFF_CS1  (N_*E_)                 // 256 floats
#define OFF_W1K  (OFF_CS1 + ER_)         // bf16 256*512
#define OFF_W2X  (OFF_W1K + ER_*L_/2)    // bf16 720*288
#define OFF_HG   (OFF_W2X + P_*KB2/2)    // bf16 64*384*288 = 3,538,944 floats
// total ~14.9 MB

__device__ __forceinline__ unsigned short f2bf(float f) {
    unsigned u = __float_as_uint(f);
    u += 0x7fffu + ((u >> 16) & 1u);
    return (unsigned short)(u >> 16);
}
__device__ __forceinline__ float bf2f(unsigned short h) {
    return __uint_as_float(((unsigned)h) << 16);
}

// ---------------- router ----------------------------------------------------
__global__ void router_kernel(const float* __restrict__ ident,
                              const float* __restrict__ rw1, const float* __restrict__ rb1,
                              const float* __restrict__ rw2, const float* __restrict__ rb2,
                              float* __restrict__ gate) {
    int n = blockIdx.x;
    int t = threadIdx.x;  // 0..63
    __shared__ float hid[H_];
    __shared__ float lg[E_];
    float acc = rb1[t];
    #pragma unroll
    for (int c = 0; c < CID_; ++c)
        acc = fmaf(ident[n*CID_ + c], rw1[c*H_ + t], acc);
    hid[t] = fmaxf(acc, 0.f);
    __syncthreads();
    if (t < E_) {
        float a = rb2[t];
        #pragma unroll
        for (int h = 0; h < H_; ++h) a = fmaf(hid[h], rw2[h*E_ + t], a);
        lg[t] = a;
    }
    __syncthreads();
    if (t == 0) {
        float m = lg[0];
        #pragma unroll
        for (int e = 1; e < E_; ++e) m = fmaxf(m, lg[e]);
        float s = 0.f, ex[E_];
        #pragma unroll
        for (int e = 0; e < E_; ++e) { ex[e] = expf(lg[e] - m); s += ex[e]; }
        float inv = 1.f / s;
        #pragma unroll
        for (int e = 0; e < E_; ++e) gate[n*E_ + e] = ex[e] * inv;
    }
}

// ---------------- prep: w1k [er][l], w2x [p][288], cs1 ----------------------
__global__ void prep_kernel(const float* __restrict__ w1, const float* __restrict__ w2,
                            const float* __restrict__ bias,
                            unsigned short* __restrict__ w1k, unsigned short* __restrict__ w2x,
                            float* __restrict__ cs1) {
    __shared__ float red[16][32];
    int bid = blockIdx.x, t = threadIdx.x;
    if (bid < 256) {                  // w1k [er][l]: 256*512 elems
        int g = bid*512 + t;
        int er = g >> 9, l = g & 511;
        w1k[g] = f2bf(w1[(size_t)(er >> 5)*(L_*R_) + (size_t)l*R_ + (er & 31)]);
    } else if (bid < 256 + 720) {     // w2x row p: K-extended
        int p = bid - 256;
        if (t < KB2) {
            unsigned short v;
            if (t < ER_)            v = f2bf(w2[(size_t)t*P_ + p]);
            else if (t < ER_ + E_)  v = f2bf(bias[(size_t)(t - ER_)*P_ + p]);
            else if (t == ER_ + E_) v = 0x3f80;  // bf16(1.0) for the mean lane
            else                    v = 0;
            w2x[(size_t)p*KB2 + t] = v;
        }
    } else {                          // cs1: 8 blocks, one expert each
        int e = bid - 976;
        int q = t >> 5, r = t & 31;
        float s = 0.f;
        for (int l = q; l < L_; l += 16)
            s += bf2f(f2bf(w1[(size_t)e*(L_*R_) + (size_t)l*R_ + r]));
        red[q][r] = s;
        __syncthreads();
        if (q == 0) {
            #pragma unroll
            for (int qq = 1; qq < 16; ++qq) s += red[qq][r];
            cs1[e*32 + r] = s;
        }
    }
}

// ---------------- GEMM1: hg[b][n][er] + K-ext cols, er split in halves ------
// grid 768 = 8 xcd * (8 b * (6 nt * 2 mh)); BM=128, BN=64, BK=32, 16 steps.
__global__ __launch_bounds__(512, 6) void gemm1_kernel(
        const float* __restrict__ x, const unsigned short* __restrict__ w1k,
        const float* __restrict__ gate, const float* __restrict__ cs1,
        unsigned short* __restrict__ hg) {
    __shared__ unsigned short As[2][128][40];   // 20480 B
    __shared__ unsigned short Bs[2][64][40];    // 10240 B
    __shared__ float red1[8][64], red2[8][64];  // 4096 B
    __shared__ float meanS[64], sdS[64];

    const int bid = blockIdx.x;
    const int xcd = bid & 7;
    const int idx = bid >> 3;            // 0..95
    const int b   = (xcd << 3) + idx / 12;
    const int rem = idx % 12;
    const int mh  = rem & 1;             // er-half; pair adjacent for x L2 reuse
    const int n0  = (rem >> 1) * 64;
    const int m0  = mh * 128;

    const int tid  = threadIdx.x;
    const int lane = tid & 63;
    const int wave = tid >> 6;          // 0..7
    const int wm = wave >> 1;           // 0..3: er-base wm*32
    const int wn = wave & 1;            // n-base wn*32
    const int l15  = lane & 15;
    const int kgrp = lane >> 4;

    const int arow = tid >> 2;          // 0..127
    const int acol = (tid & 3) * 8;     // 0,8,16,24
    const int xn  = tid & 63;
    const int xkb = wave * 4;           // 0..28
    const float* xb = x + (size_t)b * L_ * N_;
    const int gn = n0 + xn;
    const bool nvalid = (gn < N_);

    float s1 = 0.f, s2 = 0.f;
    float xr[3][4];
    u16x8 ar[2];

    f32x4 acc[2][2];
    #pragma unroll
    for (int i = 0; i < 2; ++i)
        #pragma unroll
        for (int j = 0; j < 2; ++j) acc[i][j] = (f32x4){0.f,0.f,0.f,0.f};

#define LOADX(s_, t_) { const int k0 = (t_)*32;                                  \
    _Pragma("unroll")                                                            \
    for (int i_ = 0; i_ < 4; ++i_)                                               \
        xr[s_][i_] = nvalid ? xb[(size_t)(k0 + xkb + i_)*N_ + gn] : 0.f; }
#define LOADA(s_, t_) {                                                          \
    ar[s_] = *(const u16x8*)&w1k[(size_t)(m0 + arow)*L_ + (t_)*32 + acol]; }
#define STAGE(nb_, xs_, as_) {                                                   \
    *(u16x8*)&As[nb_][arow][acol] = ar[as_];                                     \
    u16x4 bp_;                                                                   \
    _Pragma("unroll")                                                            \
    for (int i_ = 0; i_ < 4; ++i_) {                                             \
        float v_ = xr[xs_][i_]; s1 += v_; s2 = fmaf(v_, v_, s2);                 \
        bp_[i_] = f2bf(v_); }                                                    \
    *(u16x4*)&Bs[nb_][xn][xkb] = bp_; }

    LOADX(0, 0); LOADA(0, 0);
    LOADX(1, 1); LOADA(1, 1);
    LOADX(2, 2);
    STAGE(0, 0, 0);
    __syncthreads();

    #pragma unroll
    for (int t = 0; t < 16; ++t) {
        const int cur = t & 1;
        if (t + 3 < 16) LOADX((t + 3) % 3, t + 3);
        if (t + 2 < 16) LOADA((t + 2) & 1, t + 2);
        bf16x8 af[2], bfv[2];
        #pragma unroll
        for (int fm = 0; fm < 2; ++fm)
            af[fm] = *(const bf16x8*)&As[cur][wm*32 + fm*16 + l15][kgrp*8];
        #pragma unroll
        for (int fn = 0; fn < 2; ++fn)
            bfv[fn] = *(const bf16x8*)&Bs[cur][wn*32 + fn*16 + l15][kgrp*8];
        #pragma unroll
        for (int fm = 0; fm < 2; ++fm)
            #pragma unroll
            for (int fn = 0; fn < 2; ++fn)
                acc[fm][fn] = __builtin_amdgcn_mfma_f32_16x16x32_bf16(af[fm], bfv[fn], acc[fm][fn], 0, 0, 0);
        if (t < 15) STAGE((t + 1) & 1, (t + 1) % 3, (t + 1) & 1);
        __syncthreads();
    }

    // ---- fused stats (both er-halves compute; LDS-local only) ----
    red1[wave][xn] = s1;
    red2[wave][xn] = s2;
    __syncthreads();
    if (tid < 64) {
        float a = 0.f, q = 0.f;
        #pragma unroll
        for (int kk = 0; kk < 8; ++kk) { a += red1[kk][tid]; q += red2[kk][tid]; }
        float mean = a * (1.f/L_);
        float var = (q - (float)L_*mean*mean) * (1.f/(L_-1));
        var = fmaxf(var, 0.f);
        meanS[tid] = mean;
        sdS[tid]   = sqrtf(var) + 1e-6f;
    }
    __syncthreads();

    // ---- epilogue: hg[b][n0+nl][er], aligned 8B stores, rows 576 B ----
    unsigned short* hgb = hg + ((size_t)b * HGROWS + n0) * KB2;
    #pragma unroll
    for (int fm = 0; fm < 2; ++fm) {
        int er0 = m0 + wm*32 + fm*16 + kgrp*4;
        int e = er0 >> 5;
        f32x4 c4 = *(const f32x4*)&cs1[er0];
        #pragma unroll
        for (int fn = 0; fn < 2; ++fn) {
            int nl = wn*32 + fn*16 + l15;
            int gnn = n0 + nl; if (gnn > N_-1) gnn = N_-1;
            float g = gate[gnn*E_ + e];
            float m = meanS[nl];
            u16x4 pk;
            #pragma unroll
            for (int j = 0; j < 4; ++j)
                pk[j] = f2bf(g * (acc[fm][fn][j] - m * c4[j]));
            *(u16x4*)&hgb[(size_t)nl*KB2 + er0] = pk;
        }
    }
    if (mh == 0) {   // K-extension cols 256..287, all 64 rows (512 thr = 64x8)
        int nl = tid >> 3, seg = tid & 7;
        int gnn = n0 + nl; if (gnn > N_-1) gnn = N_-1;
        float sd = sdS[nl], m = meanS[nl];
        u16x4 pk;
        #pragma unroll
        for (int jj = 0; jj < 4; ++jj) {
            int k = seg*4 + jj;
            float v = (k < E_) ? gate[gnn*E_ + k] * sd : ((k == E_) ? m : 0.f);
            pk[jj] = f2bf(v);
        }
        *(u16x4*)&hgb[(size_t)nl*KB2 + ER_ + seg*4] = pk;
    }
#undef LOADX
#undef LOADA
#undef STAGE
}

// ---------------- GEMM2: out = w2x . hg^T, one LDS stage + barrier ----------
// grid 2304 = 8 xcd * (8 b * (6 pt * 6 nt)); BM=128 p, BN=64 n, K=288.
#define HGS 296   // u16 LDS stride (148 dw -> 2-way aliasing, free)
__global__ __launch_bounds__(512, 6) void gemm2_kernel(
        const unsigned short* __restrict__ hg, const unsigned short* __restrict__ w2x,
        float* __restrict__ out) {
    __shared__ __align__(16) char smem[64 * HGS * 2];      // 37888 B
    unsigned short* hgL = (unsigned short*)smem;           // [64][296]
    // patch unions hgL after the post-K barrier: per wave f32 [16][68]
    const int bid = blockIdx.x;
    const int xcd = bid & 7;
    const int idx = bid >> 3;            // 0..287
    const int b   = (xcd << 3) + idx / 36;
    const int rem = idx % 36;
    const int p0  = (rem / 6) * 128;
    const int n0  = (rem % 6) * 64;

    const int tid  = threadIdx.x;
    const int lane = tid & 63;
    const int wave = tid >> 6;
    const int l15  = lane & 15;
    const int kgrp = lane >> 4;

    // stage hg tile [64][288] -> LDS (16B chunks, 36 per row)
    const unsigned short* hgb = hg + ((size_t)b * HGROWS + n0) * KB2;
    #pragma unroll
    for (int it = 0; it < 5; ++it) {
        int c = tid + it*512;
        if (c < 64*36) {
            int row = c / 36, col = c % 36;
            *(u16x8*)&hgL[(size_t)row*HGS + col*8] =
                *(const u16x8*)&hgb[(size_t)row*KB2 + col*8];
        }
    }
    __syncthreads();

    // K-loop: wave owns 16 p-rows; A-frags from L2-hot w2x, B-frags from LDS
    int prow = p0 + wave*16 + l15; if (prow > P_-1) prow = P_-1;
    const unsigned short* ap = w2x + (size_t)prow*KB2;
    f32x4 o[4];
    #pragma unroll
    for (int j = 0; j < 4; ++j) o[j] = (f32x4){0.f,0.f,0.f,0.f};
    #pragma unroll
    for (int ks = 0; ks < 9; ++ks) {
        bf16x8 afr = *(const bf16x8*)&ap[ks*32 + kgrp*8];
        #pragma unroll
        for (int fn = 0; fn < 4; ++fn) {
            bf16x8 bfr = *(const bf16x8*)&hgL[(size_t)(fn*16 + l15)*HGS + ks*32 + kgrp*8];
            o[fn] = __builtin_amdgcn_mfma_f32_16x16x32_bf16(afr, bfr, o[fn], 0, 0, 0);
        }
    }
    __syncthreads();   // all waves done reading hgL; patch may overwrite

    // patch-transpose: D rows p_loc = kgrp*4+j, cols n_loc = fn*16+l15
    float* patch = (float*)smem + wave * 1088;   // [16][68] f32 = 4352 B
    #pragma unroll
    for (int fn = 0; fn < 4; ++fn)
        #pragma unroll
        for (int j = 0; j < 4; ++j)
            patch[(kgrp*4 + j)*68 + fn*16 + l15] = o[fn][j];
    // compiler inserts lgkmcnt for the write->read dependence (wave-private)
    const int pw0 = p0 + wave*16;
    #pragma unroll
    for (int pass = 0; pass < 4; ++pass) {
        int ploc = pass*4 + kgrp;
        f32x4 v = *(const f32x4*)&patch[ploc*68 + l15*4];
        int p = pw0 + ploc;
        int n = n0 + l15*4;
        if (p < P_) {
            float* orow = out + ((size_t)b*P_ + p)*N_;
            if (n + 3 < N_) {
                *(f32x4*)&orow[n] = v;
            } else {
                #pragma unroll
                for (int j = 0; j < 4; ++j)
                    if (n + j < N_) orow[n + j] = v[j];
            }
        }
    }
}

extern "C" void kernel_launch(void* const* d_in, const int* in_sizes, int n_in,
                              void* d_out, int out_size, void* d_ws, size_t ws_size,
                              hipStream_t stream) {
    const float* x     = (const float*)d_in[0];
    const float* ident = (const float*)d_in[1];
    const float* rw1   = (const float*)d_in[2];
    const float* rb1   = (const float*)d_in[3];
    const float* rw2   = (const float*)d_in[4];
    const float* rb2   = (const float*)d_in[5];
    const float* w1    = (const float*)d_in[6];
    const float* w2    = (const float*)d_in[7];
    const float* bias  = (const float*)d_in[8];
    float* out = (float*)d_out;
    float* ws  = (float*)d_ws;

    float* gate = ws + OFF_GATE;
    float* cs1  = ws + OFF_CS1;
    unsigned short* w1k = (unsigned short*)(ws + OFF_W1K);
    unsigned short* w2x = (unsigned short*)(ws + OFF_W2X);
    unsigned short* hg  = (unsigned short*)(ws + OFF_HG);

    router_kernel<<<N_, 64, 0, stream>>>(ident, rw1, rb1, rw2, rb2, gate);
    prep_kernel<<<256 + 720 + 8, 512, 0, stream>>>(w1, w2, bias, w1k, w2x, cs1);
    gemm1_kernel<<<dim3(768), 512, 0, stream>>>(x, w1k, gate, cs1, hg);
    gemm2_kernel<<<dim3(2304), 512, 0, stream>>>(hg, w2x, out);
}

// Round 9
// 78.039 us; speedup vs baseline: 3.1275x; 1.1320x over previous
//
#include <hip/hip_runtime.h>
#include <math.h>

#define B_ 64
#define L_ 512
#define N_ 321
#define P_ 720
#define E_ 8
#define R_ 32
#define CID_ 32
#define H_ 64
#define ER_ 256
#define KB2 288      // ER_ + 8 bias-rank + 1 mean + 23 zero-pad
#define HGROWS 384   // 6 n-tiles x 64 (rows >= N_ hold junk, never used)

typedef __attribute__((ext_vector_type(8))) short bf16x8;
typedef __attribute__((ext_vector_type(4))) float f32x4;
typedef __attribute__((ext_vector_type(8))) unsigned short u16x8;
typedef __attribute__((ext_vector_type(4))) unsigned short u16x4;

// workspace layout (float offsets)
#define OFF_GATE 0                       // N*E = 2568
#define OFF_CS1  (N_*E_)                 // 256 floats
#define OFF_W1K  (OFF_CS1 + ER_)         // bf16 256*512
#define OFF_W2X  (OFF_W1K + ER_*L_/2)    // bf16 720*288
#define OFF_HG   (OFF_W2X + P_*KB2/2)    // bf16 64*384*288
// total ~14.9 MB

__device__ __forceinline__ unsigned short f2bf(float f) {
    unsigned u = __float_as_uint(f);
    u += 0x7fffu + ((u >> 16) & 1u);
    return (unsigned short)(u >> 16);
}
__device__ __forceinline__ float bf2f(unsigned short h) {
    return __uint_as_float(((unsigned)h) << 16);
}

// ---------------- router ----------------------------------------------------
__global__ void router_kernel(const float* __restrict__ ident,
                              const float* __restrict__ rw1, const float* __restrict__ rb1,
                              const float* __restrict__ rw2, const float* __restrict__ rb2,
                              float* __restrict__ gate) {
    int n = blockIdx.x;
    int t = threadIdx.x;  // 0..63
    __shared__ float hid[H_];
    __shared__ float lg[E_];
    float acc = rb1[t];
    #pragma unroll
    for (int c = 0; c < CID_; ++c)
        acc = fmaf(ident[n*CID_ + c], rw1[c*H_ + t], acc);
    hid[t] = fmaxf(acc, 0.f);
    __syncthreads();
    if (t < E_) {
        float a = rb2[t];
        #pragma unroll
        for (int h = 0; h < H_; ++h) a = fmaf(hid[h], rw2[h*E_ + t], a);
        lg[t] = a;
    }
    __syncthreads();
    if (t == 0) {
        float m = lg[0];
        #pragma unroll
        for (int e = 1; e < E_; ++e) m = fmaxf(m, lg[e]);
        float s = 0.f, ex[E_];
        #pragma unroll
        for (int e = 0; e < E_; ++e) { ex[e] = expf(lg[e] - m); s += ex[e]; }
        float inv = 1.f / s;
        #pragma unroll
        for (int e = 0; e < E_; ++e) gate[n*E_ + e] = ex[e] * inv;
    }
}

// ---------------- prep: w1k [er][l], w2x [p][288], cs1 ----------------------
__global__ void prep_kernel(const float* __restrict__ w1, const float* __restrict__ w2,
                            const float* __restrict__ bias,
                            unsigned short* __restrict__ w1k, unsigned short* __restrict__ w2x,
                            float* __restrict__ cs1) {
    __shared__ float red[16][32];
    int bid = blockIdx.x, t = threadIdx.x;
    if (bid < 256) {                  // w1k [er][l]: 256*512 elems
        int g = bid*512 + t;
        int er = g >> 9, l = g & 511;
        w1k[g] = f2bf(w1[(size_t)(er >> 5)*(L_*R_) + (size_t)l*R_ + (er & 31)]);
    } else if (bid < 256 + 720) {     // w2x row p: K-extended
        int p = bid - 256;
        if (t < KB2) {
            unsigned short v;
            if (t < ER_)            v = f2bf(w2[(size_t)t*P_ + p]);
            else if (t < ER_ + E_)  v = f2bf(bias[(size_t)(t - ER_)*P_ + p]);
            else if (t == ER_ + E_) v = 0x3f80;  // bf16(1.0) for the mean lane
            else                    v = 0;
            w2x[(size_t)p*KB2 + t] = v;
        }
    } else {                          // cs1: 8 blocks, one expert each
        int e = bid - 976;
        int q = t >> 5, r = t & 31;
        float s = 0.f;
        for (int l = q; l < L_; l += 16)
            s += bf2f(f2bf(w1[(size_t)e*(L_*R_) + (size_t)l*R_ + r]));
        red[q][r] = s;
        __syncthreads();
        if (q == 0) {
            #pragma unroll
            for (int qq = 1; qq < 16; ++qq) s += red[qq][r];
            cs1[e*32 + r] = s;
        }
    }
}

// ---------------- GEMM1: hg[b][n][0:288] -------------------------------------
// BM=256 (full er) + K-ext, BN=64, BK=32, 16 steps, reg-ring dbuf, fused stats.
// grid 384 = 8 xcd * (8 b * 6 nt): x read ONCE, hg rows single-writer.
__global__ __launch_bounds__(512, 4) void gemm1_kernel(
        const float* __restrict__ x, const unsigned short* __restrict__ w1k,
        const float* __restrict__ gate, const float* __restrict__ cs1,
        unsigned short* __restrict__ hg) {
    __shared__ unsigned short As[2][256][40];   // 40960 B
    __shared__ unsigned short Bs[2][64][40];    // 10240 B
    __shared__ float red1[8][64], red2[8][64];  // 4096 B
    __shared__ float meanS[64], sdS[64];

    const int bid = blockIdx.x;
    const int xcd = bid & 7;
    const int idx = bid >> 3;            // 0..47
    const int b   = (xcd << 3) + idx / 6;
    const int n0  = (idx % 6) * 64;

    const int tid  = threadIdx.x;
    const int lane = tid & 63;
    const int wave = tid >> 6;          // 0..7
    const int wm = wave >> 1;           // er-base = wm*64
    const int wn = wave & 1;            // n-base = wn*32
    const int l15  = lane & 15;
    const int kgrp = lane >> 4;

    const int arow = tid >> 1;          // 0..255
    const int acol = (tid & 1) * 16;    // 0/16
    const int xn  = tid & 63;
    const int xkb = wave * 4;           // 0..28
    const float* xb = x + (size_t)b * L_ * N_;
    const int gn = n0 + xn;
    const bool nvalid = (gn < N_);

    float s1 = 0.f, s2 = 0.f;
    float xr[3][4];
    u16x8 ar[2][2];

    f32x4 acc[4][2];
    #pragma unroll
    for (int i = 0; i < 4; ++i)
        #pragma unroll
        for (int j = 0; j < 2; ++j) acc[i][j] = (f32x4){0.f,0.f,0.f,0.f};

#define LOADX(s_, t_) { const int k0 = (t_)*32;                                  \
    _Pragma("unroll")                                                            \
    for (int i_ = 0; i_ < 4; ++i_)                                               \
        xr[s_][i_] = nvalid ? xb[(size_t)(k0 + xkb + i_)*N_ + gn] : 0.f; }
#define LOADA(s_, t_) { const int k0 = (t_)*32;                                  \
    ar[s_][0] = *(const u16x8*)&w1k[(size_t)arow*L_ + k0 + acol];                \
    ar[s_][1] = *(const u16x8*)&w1k[(size_t)arow*L_ + k0 + acol + 8]; }
#define STAGE(nb_, xs_, as_) {                                                   \
    *(u16x8*)&As[nb_][arow][acol]     = ar[as_][0];                              \
    *(u16x8*)&As[nb_][arow][acol + 8] = ar[as_][1];                              \
    u16x4 bp_;                                                                   \
    _Pragma("unroll")                                                            \
    for (int i_ = 0; i_ < 4; ++i_) {                                             \
        float v_ = xr[xs_][i_]; s1 += v_; s2 = fmaf(v_, v_, s2);                 \
        bp_[i_] = f2bf(v_); }                                                    \
    *(u16x4*)&Bs[nb_][xn][xkb] = bp_; }

    LOADX(0, 0); LOADA(0, 0);
    LOADX(1, 1); LOADA(1, 1);
    LOADX(2, 2);
    STAGE(0, 0, 0);
    __syncthreads();

    #pragma unroll
    for (int t = 0; t < 16; ++t) {
        const int cur = t & 1;
        if (t + 3 < 16) LOADX((t + 3) % 3, t + 3);
        if (t + 2 < 16) LOADA((t + 2) & 1, t + 2);
        bf16x8 af[4], bfv[2];
        #pragma unroll
        for (int fm = 0; fm < 4; ++fm)
            af[fm] = *(const bf16x8*)&As[cur][wm*64 + fm*16 + l15][kgrp*8];
        #pragma unroll
        for (int fn = 0; fn < 2; ++fn)
            bfv[fn] = *(const bf16x8*)&Bs[cur][wn*32 + fn*16 + l15][kgrp*8];
        #pragma unroll
        for (int fm = 0; fm < 4; ++fm)
            #pragma unroll
            for (int fn = 0; fn < 2; ++fn)
                acc[fm][fn] = __builtin_amdgcn_mfma_f32_16x16x32_bf16(af[fm], bfv[fn], acc[fm][fn], 0, 0, 0);
        if (t < 15) STAGE((t + 1) & 1, (t + 1) % 3, (t + 1) & 1);
        __syncthreads();
    }

    // ---- fused stats ----
    red1[wave][xn] = s1;
    red2[wave][xn] = s2;
    __syncthreads();
    if (tid < 64) {
        float a = 0.f, q = 0.f;
        #pragma unroll
        for (int kk = 0; kk < 8; ++kk) { a += red1[kk][tid]; q += red2[kk][tid]; }
        float mean = a * (1.f/L_);
        float var = (q - (float)L_*mean*mean) * (1.f/(L_-1));
        var = fmaxf(var, 0.f);
        meanS[tid] = mean;
        sdS[tid]   = sqrtf(var) + 1e-6f;
    }
    __syncthreads();

    // ---- epilogue: hg[b][n0+nl][er 0..255] + ext, whole rows, one writer ----
    unsigned short* hgb = hg + ((size_t)b * HGROWS + n0) * KB2;
    #pragma unroll
    for (int fm = 0; fm < 4; ++fm) {
        int er0 = wm*64 + fm*16 + kgrp*4;
        int e = er0 >> 5;
        f32x4 c4 = *(const f32x4*)&cs1[er0];
        #pragma unroll
        for (int fn = 0; fn < 2; ++fn) {
            int nl = wn*32 + fn*16 + l15;
            int gnn = n0 + nl; if (gnn > N_-1) gnn = N_-1;
            float g = gate[gnn*E_ + e];
            float m = meanS[nl];
            u16x4 pk;
            #pragma unroll
            for (int j = 0; j < 4; ++j)
                pk[j] = f2bf(g * (acc[fm][fn][j] - m * c4[j]));
            *(u16x4*)&hgb[(size_t)nl*KB2 + er0] = pk;
        }
    }
    {   // K-extension cols 256..287, 64 rows x 8 segs (512 threads)
        int nl = tid >> 3, seg = tid & 7;
        int gnn = n0 + nl; if (gnn > N_-1) gnn = N_-1;
        float sd = sdS[nl], m = meanS[nl];
        u16x4 pk;
        #pragma unroll
        for (int jj = 0; jj < 4; ++jj) {
            int k = seg*4 + jj;
            float v = (k < E_) ? gate[gnn*E_ + k] * sd : ((k == E_) ? m : 0.f);
            pk[jj] = f2bf(v);
        }
        *(u16x4*)&hgb[(size_t)nl*KB2 + ER_ + seg*4] = pk;
    }
#undef LOADX
#undef LOADA
#undef STAGE
}

// ---------------- GEMM2: out = w2x . hg^T, one LDS stage + barrier ----------
// grid 2304 = 8 xcd * (8 b * (6 pt * 6 nt)); BM=128 p, BN=64 n, K=288.
#define HGS 296   // u16 LDS stride (148 dw -> 2-way aliasing, free)
__global__ __launch_bounds__(512, 6) void gemm2_kernel(
        const unsigned short* __restrict__ hg, const unsigned short* __restrict__ w2x,
        float* __restrict__ out) {
    __shared__ __align__(16) char smem[64 * HGS * 2];      // 37888 B
    unsigned short* hgL = (unsigned short*)smem;           // [64][296]
    const int bid = blockIdx.x;
    const int xcd = bid & 7;
    const int idx = bid >> 3;            // 0..287
    const int b   = (xcd << 3) + idx / 36;
    const int rem = idx % 36;
    const int p0  = (rem / 6) * 128;
    const int n0  = (rem % 6) * 64;

    const int tid  = threadIdx.x;
    const int lane = tid & 63;
    const int wave = tid >> 6;
    const int l15  = lane & 15;
    const int kgrp = lane >> 4;

    // stage hg tile [64][288] -> LDS (16B chunks, 36 per row)
    const unsigned short* hgb = hg + ((size_t)b * HGROWS + n0) * KB2;
    #pragma unroll
    for (int it = 0; it < 5; ++it) {
        int c = tid + it*512;
        if (c < 64*36) {
            int row = c / 36, col = c % 36;
            *(u16x8*)&hgL[(size_t)row*HGS + col*8] =
                *(const u16x8*)&hgb[(size_t)row*KB2 + col*8];
        }
    }
    __syncthreads();

    // K-loop: wave owns 16 p-rows; A-frags from L2-hot w2x, B-frags from LDS
    int prow = p0 + wave*16 + l15; if (prow > P_-1) prow = P_-1;
    const unsigned short* ap = w2x + (size_t)prow*KB2;
    f32x4 o[4];
    #pragma unroll
    for (int j = 0; j < 4; ++j) o[j] = (f32x4){0.f,0.f,0.f,0.f};
    #pragma unroll
    for (int ks = 0; ks < 9; ++ks) {
        bf16x8 afr = *(const bf16x8*)&ap[ks*32 + kgrp*8];
        #pragma unroll
        for (int fn = 0; fn < 4; ++fn) {
            bf16x8 bfr = *(const bf16x8*)&hgL[(size_t)(fn*16 + l15)*HGS + ks*32 + kgrp*8];
            o[fn] = __builtin_amdgcn_mfma_f32_16x16x32_bf16(afr, bfr, o[fn], 0, 0, 0);
        }
    }
    __syncthreads();   // all waves done reading hgL; patch may overwrite

    // patch-transpose: D rows p_loc = kgrp*4+j, cols n_loc = fn*16+l15
    float* patch = (float*)smem + wave * 1088;   // [16][68] f32 = 4352 B
    #pragma unroll
    for (int fn = 0; fn < 4; ++fn)
        #pragma unroll
        for (int j = 0; j < 4; ++j)
            patch[(kgrp*4 + j)*68 + fn*16 + l15] = o[fn][j];
    const int pw0 = p0 + wave*16;
    #pragma unroll
    for (int pass = 0; pass < 4; ++pass) {
        int ploc = pass*4 + kgrp;
        f32x4 v = *(const f32x4*)&patch[ploc*68 + l15*4];
        int p = pw0 + ploc;
        int n = n0 + l15*4;
        if (p < P_) {
            float* orow = out + ((size_t)b*P_ + p)*N_;
            if (n + 3 < N_) {
                *(f32x4*)&orow[n] = v;
            } else {
                #pragma unroll
                for (int j = 0; j < 4; ++j)
                    if (n + j < N_) orow[n + j] = v[j];
            }
        }
    }
}

extern "C" void kernel_launch(void* const* d_in, const int* in_sizes, int n_in,
                              void* d_out, int out_size, void* d_ws, size_t ws_size,
                              hipStream_t stream) {
    const float* x     = (const float*)d_in[0];
    const float* ident = (const float*)d_in[1];
    const float* rw1   = (const float*)d_in[2];
    const float* rb1   = (const float*)d_in[3];
    const float* rw2   = (const float*)d_in[4];
    const float* rb2   = (const float*)d_in[5];
    const float* w1    = (const float*)d_in[6];
    const float* w2    = (const float*)d_in[7];
    const float* bias  = (const float*)d_in[8];
    float* out = (float*)d_out;
    float* ws  = (float*)d_ws;

    float* gate = ws + OFF_GATE;
    float* cs1  = ws + OFF_CS1;
    unsigned short* w1k = (unsigned short*)(ws + OFF_W1K);
    unsigned short* w2x = (unsigned short*)(ws + OFF_W2X);
    unsigned short* hg  = (unsigned short*)(ws + OFF_HG);

    router_kernel<<<N_, 64, 0, stream>>>(ident, rw1, rb1, rw2, rb2, gate);
    prep_kernel<<<256 + 720 + 8, 512, 0, stream>>>(w1, w2, bias, w1k, w2x, cs1);
    gemm1_kernel<<<dim3(384), 512, 0, stream>>>(x, w1k, gate, cs1, hg);
    gemm2_kernel<<<dim3(2304), 512, 0, stream>>>(hg, w2x, out);
}

// Round 10
// 67.520 us; speedup vs baseline: 3.6147x; 1.1558x over previous
//
#include <hip/hip_runtime.h>
#include <math.h>

#define B_ 64
#define L_ 512
#define N_ 321
#define P_ 720
#define E_ 8
#define R_ 32
#define CID_ 32
#define H_ 64
#define ER_ 256
#define KB2 288      // ER_ + 8 bias-rank + 1 mean + 23 zero-pad
#define HGROWS 384   // 6 n-tiles x 64 (rows >= N_ hold junk, never used)

typedef __attribute__((ext_vector_type(8))) short bf16x8;
typedef __attribute__((ext_vector_type(4))) float f32x4;
typedef __attribute__((ext_vector_type(8))) unsigned short u16x8;
typedef __attribute__((ext_vector_type(4))) unsigned short u16x4;

// workspace layout (float offsets)
#define OFF_GATE 0                       // N*E = 2568
#define OFF_CS1  (N_*E_)                 // 256 floats
#define OFF_W1K  (OFF_CS1 + ER_)         // bf16 256*512
#define OFF_W2X  (OFF_W1K + ER_*L_/2)    // bf16 720*288
#define OFF_HG   (OFF_W2X + P_*KB2/2)    // bf16 64*384*288
// total ~14.9 MB

__device__ __forceinline__ unsigned short f2bf(float f) {
    unsigned u = __float_as_uint(f);
    u += 0x7fffu + ((u >> 16) & 1u);
    return (unsigned short)(u >> 16);
}
__device__ __forceinline__ float bf2f(unsigned short h) {
    return __uint_as_float(((unsigned)h) << 16);
}

// ---------------- router ----------------------------------------------------
__global__ void router_kernel(const float* __restrict__ ident,
                              const float* __restrict__ rw1, const float* __restrict__ rb1,
                              const float* __restrict__ rw2, const float* __restrict__ rb2,
                              float* __restrict__ gate) {
    int n = blockIdx.x;
    int t = threadIdx.x;  // 0..63
    __shared__ float hid[H_];
    __shared__ float lg[E_];
    float acc = rb1[t];
    #pragma unroll
    for (int c = 0; c < CID_; ++c)
        acc = fmaf(ident[n*CID_ + c], rw1[c*H_ + t], acc);
    hid[t] = fmaxf(acc, 0.f);
    __syncthreads();
    if (t < E_) {
        float a = rb2[t];
        #pragma unroll
        for (int h = 0; h < H_; ++h) a = fmaf(hid[h], rw2[h*E_ + t], a);
        lg[t] = a;
    }
    __syncthreads();
    if (t == 0) {
        float m = lg[0];
        #pragma unroll
        for (int e = 1; e < E_; ++e) m = fmaxf(m, lg[e]);
        float s = 0.f, ex[E_];
        #pragma unroll
        for (int e = 0; e < E_; ++e) { ex[e] = expf(lg[e] - m); s += ex[e]; }
        float inv = 1.f / s;
        #pragma unroll
        for (int e = 0; e < E_; ++e) gate[n*E_ + e] = ex[e] * inv;
    }
}

// ---------------- prep: w1k [er][l], w2x [p][288], cs1 ----------------------
__global__ void prep_kernel(const float* __restrict__ w1, const float* __restrict__ w2,
                            const float* __restrict__ bias,
                            unsigned short* __restrict__ w1k, unsigned short* __restrict__ w2x,
                            float* __restrict__ cs1) {
    __shared__ float red[16][32];
    int bid = blockIdx.x, t = threadIdx.x;
    if (bid < 256) {                  // w1k [er][l]: 256*512 elems
        int g = bid*512 + t;
        int er = g >> 9, l = g & 511;
        w1k[g] = f2bf(w1[(size_t)(er >> 5)*(L_*R_) + (size_t)l*R_ + (er & 31)]);
    } else if (bid < 256 + 720) {     // w2x row p: K-extended
        int p = bid - 256;
        if (t < KB2) {
            unsigned short v;
            if (t < ER_)            v = f2bf(w2[(size_t)t*P_ + p]);
            else if (t < ER_ + E_)  v = f2bf(bias[(size_t)(t - ER_)*P_ + p]);
            else if (t == ER_ + E_) v = 0x3f80;  // bf16(1.0) for the mean lane
            else                    v = 0;
            w2x[(size_t)p*KB2 + t] = v;
        }
    } else {                          // cs1: 8 blocks, one expert each
        int e = bid - 976;
        int q = t >> 5, r = t & 31;
        float s = 0.f;
        for (int l = q; l < L_; l += 16)
            s += bf2f(f2bf(w1[(size_t)e*(L_*R_) + (size_t)l*R_ + r]));
        red[q][r] = s;
        __syncthreads();
        if (q == 0) {
            #pragma unroll
            for (int qq = 1; qq < 16; ++qq) s += red[qq][r];
            cs1[e*32 + r] = s;
        }
    }
}

// ---------------- GEMM1: stage-once x-tile, barrier-free MFMA phase ---------
// Per (b, 64n): stage x[512k][64n] -> LDS bf16 [64n][512k] (XOR-swizzled),
// fused stats in the same pass. Then each wave owns 32er x 64n x K=512,
// A-frags streamed from L2-hot w1k (reg ring), B-frags from LDS. 2 barriers.
// grid 384 = 8 xcd * (8 b * 6 nt).
#define SM_XT   0               // u16 [64][512] = 65536 B, swizzled
#define SM_RED  65536           // f32 [8][64] x2 = 4096 B
#define SM_MSD  (65536+4096)    // f32 [64] x2 = 512 B
#define SM_TOT  (65536+4096+512)

__global__ __launch_bounds__(512, 4) void gemm1_kernel(
        const float* __restrict__ x, const unsigned short* __restrict__ w1k,
        const float* __restrict__ gate, const float* __restrict__ cs1,
        unsigned short* __restrict__ hg) {
    __shared__ __align__(16) char smem[SM_TOT];
    char* xTc   = smem + SM_XT;
    float* red1 = (float*)(smem + SM_RED);     // [8][64]
    float* red2 = red1 + 512;
    float* meanS = (float*)(smem + SM_MSD);    // [64]
    float* sdS   = meanS + 64;

    const int bid = blockIdx.x;
    const int xcd = bid & 7;
    const int idx = bid >> 3;            // 0..47
    const int b   = (xcd << 3) + idx / 6;
    const int n0  = (idx % 6) * 64;

    const int tid  = threadIdx.x;
    const int lane = tid & 63;
    const int wave = tid >> 6;          // 0..7
    const int l15  = lane & 15;
    const int kgrp = lane >> 4;         // 0..3

    // ---- stage x-tile + stats: thread (xn, ks) covers 64 k for one n ----
    const int xn = tid & 63;
    const int ks8 = tid >> 6;           // 0..7, k-slice of 64
    const float* xb = x + (size_t)b * L_ * N_;
    const int gn = n0 + xn;
    const bool nvalid = (gn < N_);
    const int xsw = (xn & 7) << 4;      // row XOR swizzle (bits 4..6)

    float s1 = 0.f, s2 = 0.f;
    #pragma unroll
    for (int c8 = 0; c8 < 8; ++c8) {
        const int k0 = ks8*64 + c8*8;
        float v[8];
        #pragma unroll
        for (int j = 0; j < 8; ++j)
            v[j] = nvalid ? xb[(size_t)(k0 + j)*N_ + gn] : 0.f;
        u16x8 pk;
        #pragma unroll
        for (int j = 0; j < 8; ++j) {
            s1 += v[j]; s2 = fmaf(v[j], v[j], s2); pk[j] = f2bf(v[j]);
        }
        *(u16x8*)(xTc + xn*1024 + ((k0*2) ^ xsw)) = pk;
    }
    red1[ks8*64 + xn] = s1;
    red2[ks8*64 + xn] = s2;
    __syncthreads();

    if (tid < 64) {
        float a = 0.f, q = 0.f;
        #pragma unroll
        for (int kk = 0; kk < 8; ++kk) { a += red1[kk*64 + tid]; q += red2[kk*64 + tid]; }
        float mean = a * (1.f/L_);
        float var = (q - (float)L_*mean*mean) * (1.f/(L_-1));
        var = fmaxf(var, 0.f);
        meanS[tid] = mean;
        sdS[tid]   = sqrtf(var) + 1e-6f;
    }
    __syncthreads();

    // ---- MFMA phase: wave owns er rows wave*32..+31, K=512, no barriers ----
    const unsigned short* apA = w1k + (size_t)(wave*32 + l15)*L_;
    const unsigned short* apB = w1k + (size_t)(wave*32 + 16 + l15)*L_;
    const int rsw = (l15 & 7) << 4;     // B-frag row swizzle (row = fn*16+l15)

    f32x4 acc[2][4];
    #pragma unroll
    for (int i = 0; i < 2; ++i)
        #pragma unroll
        for (int j = 0; j < 4; ++j) acc[i][j] = (f32x4){0.f,0.f,0.f,0.f};

    bf16x8 af[4][2];
#define LDA(s_, ks_) { af[s_][0] = *(const bf16x8*)&apA[(ks_)*32 + kgrp*8];      \
                       af[s_][1] = *(const bf16x8*)&apB[(ks_)*32 + kgrp*8]; }
    LDA(0, 0); LDA(1, 1); LDA(2, 2);
    #pragma unroll
    for (int ks = 0; ks < 16; ++ks) {
        if (ks + 3 < 16) LDA((ks + 3) & 3, ks + 3);
        const int cur = ks & 3;
        const int kb = (ks*32 + kgrp*8) * 2;   // byte offset in row
        #pragma unroll
        for (int fn = 0; fn < 4; ++fn) {
            bf16x8 bfr = *(const bf16x8*)(xTc + (fn*16 + l15)*1024 + (kb ^ rsw));
            acc[0][fn] = __builtin_amdgcn_mfma_f32_16x16x32_bf16(af[cur][0], bfr, acc[0][fn], 0, 0, 0);
            acc[1][fn] = __builtin_amdgcn_mfma_f32_16x16x32_bf16(af[cur][1], bfr, acc[1][fn], 0, 0, 0);
        }
    }
#undef LDA

    // ---- epilogue: hg[b][n0+nl][er] whole rows + K-ext, no barrier needed ----
    unsigned short* hgb = hg + ((size_t)b * HGROWS + n0) * KB2;
    #pragma unroll
    for (int fm = 0; fm < 2; ++fm) {
        int er0 = wave*32 + fm*16 + kgrp*4;
        int e = er0 >> 5;
        f32x4 c4 = *(const f32x4*)&cs1[er0];
        #pragma unroll
        for (int fn = 0; fn < 4; ++fn) {
            int nl = fn*16 + l15;
            int gnn = n0 + nl; if (gnn > N_-1) gnn = N_-1;
            float g = gate[gnn*E_ + e];
            float m = meanS[nl];
            u16x4 pk;
            #pragma unroll
            for (int j = 0; j < 4; ++j)
                pk[j] = f2bf(g * (acc[fm][fn][j] - m * c4[j]));
            *(u16x4*)&hgb[(size_t)nl*KB2 + er0] = pk;
        }
    }
    {   // K-extension cols 256..287, 64 rows x 8 segs (512 threads)
        int nl = tid >> 3, seg = tid & 7;
        int gnn = n0 + nl; if (gnn > N_-1) gnn = N_-1;
        float sd = sdS[nl], m = meanS[nl];
        u16x4 pk;
        #pragma unroll
        for (int jj = 0; jj < 4; ++jj) {
            int k = seg*4 + jj;
            float v = (k < E_) ? gate[gnn*E_ + k] * sd : ((k == E_) ? m : 0.f);
            pk[jj] = f2bf(v);
        }
        *(u16x4*)&hgb[(size_t)nl*KB2 + ER_ + seg*4] = pk;
    }
}

// ---------------- GEMM2: out = w2x . hg^T, one LDS stage + barrier ----------
// grid 2304 = 8 xcd * (8 b * (6 pt * 6 nt)); BM=128 p, BN=64 n, K=288.
#define HGS 296   // u16 LDS stride (148 dw -> 2-way aliasing, free)
__global__ __launch_bounds__(512, 6) void gemm2_kernel(
        const unsigned short* __restrict__ hg, const unsigned short* __restrict__ w2x,
        float* __restrict__ out) {
    __shared__ __align__(16) char smem[64 * HGS * 2];      // 37888 B
    unsigned short* hgL = (unsigned short*)smem;           // [64][296]
    const int bid = blockIdx.x;
    const int xcd = bid & 7;
    const int idx = bid >> 3;            // 0..287
    const int b   = (xcd << 3) + idx / 36;
    const int rem = idx % 36;
    const int p0  = (rem / 6) * 128;
    const int n0  = (rem % 6) * 64;

    const int tid  = threadIdx.x;
    const int lane = tid & 63;
    const int wave = tid >> 6;
    const int l15  = lane & 15;
    const int kgrp = lane >> 4;

    // stage hg tile [64][288] -> LDS (16B chunks, 36 per row)
    const unsigned short* hgb = hg + ((size_t)b * HGROWS + n0) * KB2;
    #pragma unroll
    for (int it = 0; it < 5; ++it) {
        int c = tid + it*512;
        if (c < 64*36) {
            int row = c / 36, col = c % 36;
            *(u16x8*)&hgL[(size_t)row*HGS + col*8] =
                *(const u16x8*)&hgb[(size_t)row*KB2 + col*8];
        }
    }
    __syncthreads();

    // K-loop: wave owns 16 p-rows; A-frags from L2-hot w2x, B-frags from LDS
    int prow = p0 + wave*16 + l15; if (prow > P_-1) prow = P_-1;
    const unsigned short* ap = w2x + (size_t)prow*KB2;
    f32x4 o[4];
    #pragma unroll
    for (int j = 0; j < 4; ++j) o[j] = (f32x4){0.f,0.f,0.f,0.f};
    #pragma unroll
    for (int ks = 0; ks < 9; ++ks) {
        bf16x8 afr = *(const bf16x8*)&ap[ks*32 + kgrp*8];
        #pragma unroll
        for (int fn = 0; fn < 4; ++fn) {
            bf16x8 bfr = *(const bf16x8*)&hgL[(size_t)(fn*16 + l15)*HGS + ks*32 + kgrp*8];
            o[fn] = __builtin_amdgcn_mfma_f32_16x16x32_bf16(afr, bfr, o[fn], 0, 0, 0);
        }
    }
    __syncthreads();   // all waves done reading hgL; patch may overwrite

    // patch-transpose: D rows p_loc = kgrp*4+j, cols n_loc = fn*16+l15
    float* patch = (float*)smem + wave * 1088;   // [16][68] f32 = 4352 B
    #pragma unroll
    for (int fn = 0; fn < 4; ++fn)
        #pragma unroll
        for (int j = 0; j < 4; ++j)
            patch[(kgrp*4 + j)*68 + fn*16 + l15] = o[fn][j];
    const int pw0 = p0 + wave*16;
    #pragma unroll
    for (int pass = 0; pass < 4; ++pass) {
        int ploc = pass*4 + kgrp;
        f32x4 v = *(const f32x4*)&patch[ploc*68 + l15*4];
        int p = pw0 + ploc;
        int n = n0 + l15*4;
        if (p < P_) {
            float* orow = out + ((size_t)b*P_ + p)*N_;
            if (n + 3 < N_) {
                *(f32x4*)&orow[n] = v;
            } else {
                #pragma unroll
                for (int j = 0; j < 4; ++j)
                    if (n + j < N_) orow[n + j] = v[j];
            }
        }
    }
}

extern "C" void kernel_launch(void* const* d_in, const int* in_sizes, int n_in,
                              void* d_out, int out_size, void* d_ws, size_t ws_size,
                              hipStream_t stream) {
    const float* x     = (const float*)d_in[0];
    const float* ident = (const float*)d_in[1];
    const float* rw1   = (const float*)d_in[2];
    const float* rb1   = (const float*)d_in[3];
    const float* rw2   = (const float*)d_in[4];
    const float* rb2   = (const float*)d_in[5];
    const float* w1    = (const float*)d_in[6];
    const float* w2    = (const float*)d_in[7];
    const float* bias  = (const float*)d_in[8];
    float* out = (float*)d_out;
    float* ws  = (float*)d_ws;

    float* gate = ws + OFF_GATE;
    float* cs1  = ws + OFF_CS1;
    unsigned short* w1k = (unsigned short*)(ws + OFF_W1K);
    unsigned short* w2x = (unsigned short*)(ws + OFF_W2X);
    unsigned short* hg  = (unsigned short*)(ws + OFF_HG);

    router_kernel<<<N_, 64, 0, stream>>>(ident, rw1, rb1, rw2, rb2, gate);
    prep_kernel<<<256 + 720 + 8, 512, 0, stream>>>(w1, w2, bias, w1k, w2x, cs1);
    gemm1_kernel<<<dim3(384), 512, 0, stream>>>(x, w1k, gate, cs1, hg);
    gemm2_kernel<<<dim3(2304), 512, 0, stream>>>(hg, w2x, out);
}